// Round 7
// baseline (26.714 us; speedup 1.0000x reference)
//
#include <hip/hip_runtime.h>
#include <hip/hip_bf16.h>

// out_k(x) = sum_{a0..a3 in {0,1,2}} T_k[a] * t0[a0]*t1[a1]*t2[a2]*t3[a3],
// t_q = (1, cos x_q, sin x_q). Fully fused: every block recomputes the
// 162-float T in LDS, then streams the contraction.
// vs R3/R6 (12.19us): layer 0 collapsed to a single direct product write
// (L0A+L0B compose to A1[j][s] = prod_q g_q[s_q][j_q]; no LDS read, no
// intermediate barrier). 5 barriers total, 4 LDS round-trips.
// Register-lifetime discipline: <=4 Gates live at once (R4's full-register
// Stage A kept 8 gates + tables live and spilled: 33.9us).

__device__ __forceinline__ float2 cmul(float2 a, float2 b) {
    return make_float2(a.x*b.x - a.y*b.y, a.x*b.y + a.y*b.x);
}
__device__ __forceinline__ float2 cfma(float2 a, float2 b, float2 acc) {
    acc.x = __builtin_fmaf(a.x, b.x, __builtin_fmaf(-a.y, b.y, acc.x));
    acc.y = __builtin_fmaf(a.x, b.y, __builtin_fmaf( a.y, b.x, acc.y));
    return acc;
}
__device__ __forceinline__ float2 csel(int b, float2 a1, float2 a0) {
    return make_float2(b ? a1.x : a0.x, b ? a1.y : a0.y);
}

// ring-CNOT composed permutation for layer range r; GF(2)-linear in s.
__device__ __forceinline__ constexpr int ringperm(int s, int r) {
    int src = s;
    #pragma unroll
    for (int q = 3; q >= 0; --q) {
        const int cs = 3 - q, ts = 3 - ((q + r) & 3);
        if ((src >> cs) & 1) src ^= 1 << ts;
    }
    return src;
}

struct Gate { float2 e00, e01, e10, e11; };

__device__ __forceinline__ Gate mkgate(float phi, float th, float om) {
    const float sa = __sinf(0.5f*(phi+om)), ca = __cosf(0.5f*(phi+om));
    const float sb = __sinf(0.5f*(phi-om)), cb = __cosf(0.5f*(phi-om));
    const float sth = __sinf(0.5f*th),      cth = __cosf(0.5f*th);
    Gate g;
    g.e00 = make_float2( cth*ca, -cth*sa);
    g.e01 = make_float2(-sth*cb, -sth*sb);
    g.e10 = make_float2( sth*cb, -sth*sb);
    g.e11 = make_float2( cth*ca,  cth*sa);
    return g;
}

// entry [r][c] of a 2x2 gate
__device__ __forceinline__ float2 gent(const Gate& g, int r, int c) {
    return r ? (c ? g.e11 : g.e10) : (c ? g.e01 : g.e00);
}

template<int NE>
__global__ __launch_bounds__(256) void qnet_fused(
        const float4* __restrict__ x,   // [B] (4 angles each)
        const float*  __restrict__ w,   // [2][4][3]
        const float*  __restrict__ fcw, // [2][2]
        const float*  __restrict__ fcb, // [2]
        float2* __restrict__ out,       // [B]
        int B) {
    __shared__ float2 A[2][16][17];
    __shared__ float2 M[2][16][17];
    __shared__ float  Ts[162];

    const int t    = threadIdx.x;
    const int j    = t >> 4, sidx = t & 15;
    const int gt   = blockIdx.x * 256 + t;
    const int stride = gridDim.x * 256;

    // ---- issue x loads first (in flight during precompute) ----
    float4 xv[NE]; int ei[NE];
    #pragma unroll
    for (int jj = 0; jj < NE; ++jj) {
        ei[jj] = gt + jj * stride;
        xv[jj] = make_float4(0.f, 0.f, 0.f, 0.f);
        if (ei[jj] < B) xv[jj] = x[ei[jj]];
    }

    // ---- uniform parameter loads (vectorized, issued early) ----
    float wv[24];
    {
        const float4* w4 = (const float4*)w;
        #pragma unroll
        for (int i = 0; i < 6; ++i) {
            const float4 v = w4[i];
            wv[4*i+0] = v.x; wv[4*i+1] = v.y; wv[4*i+2] = v.z; wv[4*i+3] = v.w;
        }
    }
    const float4 FW = *(const float4*)fcw;   // w00,w01,w10,w11
    const float2 FB = *(const float2*)fcb;

    const int b3 = (sidx >> 3) & 1, b2 = (sidx >> 2) & 1;
    const int b1 = (sidx >> 1) & 1, b0 = sidx & 1;
    const int highB = sidx & 12;   // bits 3,2

    // ========== Layer 0: single direct tensor-product write ==========
    // A[1][j][s] = g0[s3][j3] * g1[s2][j2] * g2[s1][j1] * g3[s0][j0]
    {
        const Gate g0 = mkgate(wv[0], wv[1], wv[2]);
        const Gate g1 = mkgate(wv[3], wv[4], wv[5]);
        const Gate g2 = mkgate(wv[6], wv[7], wv[8]);
        const Gate g3 = mkgate(wv[9], wv[10], wv[11]);
        const int j3 = (j >> 3) & 1, j2 = (j >> 2) & 1;
        const int j1 = (j >> 1) & 1, j0 = j & 1;
        const float2 hi = cmul(gent(g0, b3, j3), gent(g1, b2, j2));
        const float2 lo = cmul(gent(g2, b1, j1), gent(g3, b0, j0));
        A[1][j][sidx] = cmul(hi, lo);
    }
    __syncthreads();                              // barrier #1

    // ========== Layer 1 (layer-0 ring perm folded into reads) ==========
    {
        const Gate g0 = mkgate(wv[12], wv[13], wv[14]);
        const Gate g1 = mkgate(wv[15], wv[16], wv[17]);
        const Gate g2 = mkgate(wv[18], wv[19], wv[20]);
        const Gate g3 = mkgate(wv[21], wv[22], wv[23]);

        // L1A: wires 0,1; source index i -> sigma0(i), sigma0 = ringperm(.,1)
        {
            constexpr int p1 = ringperm(1, 1), p2 = ringperm(2, 1);
            constexpr int p4 = ringperm(4, 1), p8 = ringperm(8, 1);
            const int sl  = (b1 ? p2 : 0) ^ (b0 ? p1 : 0);  // sigma0(lowA)
            const float2 hu0 = csel(b3, g0.e10, g0.e00), hu1 = csel(b3, g0.e11, g0.e01);
            const float2 lv0 = csel(b2, g1.e10, g1.e00), lv1 = csel(b2, g1.e11, g1.e01);
            float2 acc = make_float2(0.f, 0.f);
            acc = cfma(cmul(hu0, lv0), A[1][j][sl],           acc);
            acc = cfma(cmul(hu0, lv1), A[1][j][sl ^ p4],      acc);
            acc = cfma(cmul(hu1, lv0), A[1][j][sl ^ p8],      acc);
            acc = cfma(cmul(hu1, lv1), A[1][j][sl ^ p4 ^ p8], acc);
            A[0][j][sidx] = acc;
        }
        __syncthreads();                          // barrier #2

        // L1B: wires 2,3; read A[0] -> write A[1]
        {
            const float2 hu0 = csel(b1, g2.e10, g2.e00), hu1 = csel(b1, g2.e11, g2.e01);
            const float2 lv0 = csel(b0, g3.e10, g3.e00), lv1 = csel(b0, g3.e11, g3.e01);
            float2 acc = make_float2(0.f, 0.f);
            acc = cfma(cmul(hu0, lv0), A[0][j][highB | 0], acc);
            acc = cfma(cmul(hu0, lv1), A[0][j][highB | 1], acc);
            acc = cfma(cmul(hu1, lv0), A[0][j][highB | 2], acc);
            acc = cfma(cmul(hu1, lv1), A[0][j][highB | 3], acc);
            A[1][j][sidx] = acc;
        }
        __syncthreads();                          // barrier #3
    }

    // ---- trig for the contraction (fills LDS-latency bubbles here) ----
    float c[4][NE], s[4][NE];
    #pragma unroll
    for (int jj = 0; jj < NE; ++jj) {
        s[0][jj] = __sinf(xv[jj].x); c[0][jj] = __cosf(xv[jj].x);
        s[1][jj] = __sinf(xv[jj].y); c[1][jj] = __cosf(xv[jj].y);
        s[2][jj] = __sinf(xv[jj].z); c[2][jj] = __cosf(xv[jj].z);
        s[3][jj] = __sinf(xv[jj].w); c[3][jj] = __cosf(xv[jj].w);
    }

    // ---- Stage B: M_k[row][col] = sum_tp conj(U[tp,row]) o_k[tp] U[tp,col]
    // Final ring perm (sigma1 = ringperm(.,2)) folded: U[tp][c] = A[1][c][sigma1(tp)]
    {
        const int row = j, col = sidx;
        float2 m0 = make_float2(0.f, 0.f), m1 = make_float2(0.f, 0.f);
        #pragma unroll
        for (int tp = 0; tp < 16; ++tp) {
            const int sp = ringperm(tp, 2);
            const float z0 = 1.f - 2.f * ((tp >> 3) & 1);
            const float z1 = 1.f - 2.f * ((tp >> 2) & 1);
            const float o0 = FW.x * z0 + FW.y * z1;
            const float o1 = FW.z * z0 + FW.w * z1;
            const float2 u = A[1][row][sp];
            const float2 v = A[1][col][sp];
            const float2 cc = make_float2(u.x * v.x + u.y * v.y,
                                          u.x * v.y - u.y * v.x);
            m0.x += o0 * cc.x; m0.y += o0 * cc.y;
            m1.x += o1 * cc.x; m1.y += o1 * cc.y;
        }
        M[0][row][col] = m0;
        M[1][row][col] = m1;
    }
    __syncthreads();                              // barrier #4

    // ---- Stage C: T_k[a] = Re sum_ss M_k[ss][ss^mY] * f(a,ss)
    if (t < 162) {
        const int k = t / 81, idx = t % 81;
        const int aa[4] = {idx / 27, (idx / 9) % 3, (idx / 3) % 3, idx % 3};
        int mZ = 0, mY = 0, nY = 0;
        #pragma unroll
        for (int q = 0; q < 4; ++q) {
            if (aa[q] == 1) mZ |= 1 << (3 - q);
            else if (aa[q] == 2) { mY |= 1 << (3 - q); ++nY; }
        }
        const int  mZY   = mZ | mY;
        const bool pickY = nY & 1;
        const int  baseS = ((nY & 3) == 1 || (nY & 3) == 2) ? 1 : 0;
        const int  k0    = (nY + baseS) & 1;
        float acc = 0.f;
        #pragma unroll
        for (int ss = 0; ss < 16; ++ss) {
            const float2 m = M[k][ss][ss ^ mY];
            const float  v = pickY ? m.y : m.x;
            acc += ((__popc(ss & mZY) + k0) & 1) ? -v : v;
        }
        acc *= 0.0625f;
        if (idx == 0) acc += (k == 0 ? FB.x : FB.y);
        Ts[t] = acc;
    }
    __syncthreads();                              // barrier #5

    // ================= main contraction =================
    float res0[NE], res1[NE];
    #pragma unroll
    for (int k = 0; k < 2; ++k) {
        float fa[NE];
        #pragma unroll
        for (int a0 = 0; a0 < 3; ++a0) {
            float ga[NE];
            #pragma unroll
            for (int a1 = 0; a1 < 3; ++a1) {
                float ea[NE];
                #pragma unroll
                for (int a2 = 0; a2 < 3; ++a2) {
                    const int base = (((k * 3 + a0) * 3 + a1) * 3 + a2) * 3;
                    const float t0 = Ts[base + 0];
                    const float t1 = Ts[base + 1];
                    const float t2 = Ts[base + 2];
                    #pragma unroll
                    for (int jj = 0; jj < NE; ++jj) {
                        const float d = __builtin_fmaf(s[3][jj], t2,
                                        __builtin_fmaf(c[3][jj], t1, t0));
                        if (a2 == 0)      ea[jj] = d;
                        else if (a2 == 1) ea[jj] = __builtin_fmaf(c[2][jj], d, ea[jj]);
                        else              ea[jj] = __builtin_fmaf(s[2][jj], d, ea[jj]);
                    }
                }
                #pragma unroll
                for (int jj = 0; jj < NE; ++jj) {
                    if (a1 == 0)      ga[jj] = ea[jj];
                    else if (a1 == 1) ga[jj] = __builtin_fmaf(c[1][jj], ea[jj], ga[jj]);
                    else              ga[jj] = __builtin_fmaf(s[1][jj], ea[jj], ga[jj]);
                }
            }
            #pragma unroll
            for (int jj = 0; jj < NE; ++jj) {
                if (a0 == 0)      fa[jj] = ga[jj];
                else if (a0 == 1) fa[jj] = __builtin_fmaf(c[0][jj], ga[jj], fa[jj]);
                else              fa[jj] = __builtin_fmaf(s[0][jj], ga[jj], fa[jj]);
            }
        }
        #pragma unroll
        for (int jj = 0; jj < NE; ++jj) {
            if (k == 0) res0[jj] = fa[jj]; else res1[jj] = fa[jj];
        }
    }

    #pragma unroll
    for (int jj = 0; jj < NE; ++jj)
        if (ei[jj] < B) out[ei[jj]] = make_float2(res0[jj], res1[jj]);
}

extern "C" void kernel_launch(void* const* d_in, const int* in_sizes, int n_in,
                              void* d_out, int out_size, void* d_ws, size_t ws_size,
                              hipStream_t stream) {
    const float* x   = (const float*)d_in[0];   // [B,4]
    const float* w   = (const float*)d_in[1];   // [2,4,3]
    const float* fcw = (const float*)d_in[2];   // [2,2]
    const float* fcb = (const float*)d_in[3];   // [2]
    const int B = in_sizes[0] / 4;

    constexpr int NE = 4;
    const int threads = (B + NE - 1) / NE;
    const int blocks  = (threads + 255) / 256;
    qnet_fused<NE><<<blocks, 256, 0, stream>>>(
        (const float4*)x, w, fcw, fcb, (float2*)d_out, B);
}

// Round 8
// 12.185 us; speedup vs baseline: 2.1924x; 2.1924x over previous
//
#include <hip/hip_runtime.h>
#include <hip/hip_bf16.h>

// out_k(x) = sum_{a0..a3 in {0,1,2}} T_k[a] * t0[a0]*t1[a1]*t2[a2]*t3[a3],
// t_q = (1, cos x_q, sin x_q). Fully fused: every block recomputes the
// 162-float T in LDS, then streams the contraction.
// EXACT R3/R6 artifact (proven best: 12.192/12.193us, reproduced twice).
// Do not perturb: R4 (+21.7us, spill), R5 (+3.0us), R7 (+14.5us) all showed
// that semantically-neutral codegen changes regress this kernel in ways the
// available counters cannot attribute. This source is the measured optimum.

__device__ __forceinline__ float2 cmul(float2 a, float2 b) {
    return make_float2(a.x*b.x - a.y*b.y, a.x*b.y + a.y*b.x);
}
__device__ __forceinline__ float2 cfma(float2 a, float2 b, float2 acc) {
    acc.x = __builtin_fmaf(a.x, b.x, __builtin_fmaf(-a.y, b.y, acc.x));
    acc.y = __builtin_fmaf(a.x, b.y, __builtin_fmaf( a.y, b.x, acc.y));
    return acc;
}
__device__ __forceinline__ float2 csel(int b, float2 a1, float2 a0) {
    return make_float2(b ? a1.x : a0.x, b ? a1.y : a0.y);
}

// ring-CNOT composed permutation for layer range r; GF(2)-linear in s.
__device__ __forceinline__ constexpr int ringperm(int s, int r) {
    int src = s;
    #pragma unroll
    for (int q = 3; q >= 0; --q) {
        const int cs = 3 - q, ts = 3 - ((q + r) & 3);
        if ((src >> cs) & 1) src ^= 1 << ts;
    }
    return src;
}

struct Gate { float2 e00, e01, e10, e11; };

__device__ __forceinline__ Gate mkgate(float phi, float th, float om) {
    const float sa = __sinf(0.5f*(phi+om)), ca = __cosf(0.5f*(phi+om));
    const float sb = __sinf(0.5f*(phi-om)), cb = __cosf(0.5f*(phi-om));
    const float sth = __sinf(0.5f*th),      cth = __cosf(0.5f*th);
    Gate g;
    g.e00 = make_float2( cth*ca, -cth*sa);
    g.e01 = make_float2(-sth*cb, -sth*sb);
    g.e10 = make_float2( sth*cb, -sth*sb);
    g.e11 = make_float2( cth*ca,  cth*sa);
    return g;
}

template<int NE>
__global__ __launch_bounds__(256) void qnet_fused(
        const float4* __restrict__ x,   // [B] (4 angles each)
        const float*  __restrict__ w,   // [2][4][3]
        const float*  __restrict__ fcw, // [2][2]
        const float*  __restrict__ fcb, // [2]
        float2* __restrict__ out,       // [B]
        int B) {
    __shared__ float2 A[2][16][17];
    __shared__ float2 M[2][16][17];
    __shared__ float  Ts[162];

    const int t    = threadIdx.x;
    const int j    = t >> 4, sidx = t & 15;
    const int gt   = blockIdx.x * 256 + t;
    const int stride = gridDim.x * 256;

    // ---- issue x loads first (in flight during precompute) ----
    float4 xv[NE]; int ei[NE];
    #pragma unroll
    for (int jj = 0; jj < NE; ++jj) {
        ei[jj] = gt + jj * stride;
        xv[jj] = make_float4(0.f, 0.f, 0.f, 0.f);
        if (ei[jj] < B) xv[jj] = x[ei[jj]];
    }

    // ---- uniform parameter loads (vectorized, issued early) ----
    float wv[24];
    {
        const float4* w4 = (const float4*)w;
        #pragma unroll
        for (int i = 0; i < 6; ++i) {
            const float4 v = w4[i];
            wv[4*i+0] = v.x; wv[4*i+1] = v.y; wv[4*i+2] = v.z; wv[4*i+3] = v.w;
        }
    }
    const float4 FW = *(const float4*)fcw;   // w00,w01,w10,w11
    const float2 FB = *(const float2*)fcb;

    const int b3 = (sidx >> 3) & 1, b2 = (sidx >> 2) & 1;
    const int b1 = (sidx >> 1) & 1, b0 = sidx & 1;
    const int lowA  = sidx & 3;    // bits 1,0
    const int highB = sidx & 12;   // bits 3,2

    // ================= Layer 0 =================
    {
        const Gate g0 = mkgate(wv[0], wv[1], wv[2]);
        const Gate g1 = mkgate(wv[3], wv[4], wv[5]);
        const Gate g2 = mkgate(wv[6], wv[7], wv[8]);
        const Gate g3 = mkgate(wv[9], wv[10], wv[11]);

        // L0A: wires 0,1 applied directly to identity.
        {
            const float2 h = csel((j >> 3) & 1,
                                  csel(b3, g0.e11, g0.e01),
                                  csel(b3, g0.e10, g0.e00));
            const float2 l = csel((j >> 2) & 1,
                                  csel(b2, g1.e11, g1.e01),
                                  csel(b2, g1.e10, g1.e00));
            const float2 c = cmul(h, l);
            A[0][j][sidx] = (lowA == (j & 3)) ? c : make_float2(0.f, 0.f);
        }
        __syncthreads();

        // L0B: wires 2,3 (bits 1,0); read A[0] -> write A[1]
        {
            const float2 hu0 = csel(b1, g2.e10, g2.e00), hu1 = csel(b1, g2.e11, g2.e01);
            const float2 lv0 = csel(b0, g3.e10, g3.e00), lv1 = csel(b0, g3.e11, g3.e01);
            float2 acc = make_float2(0.f, 0.f);
            acc = cfma(cmul(hu0, lv0), A[0][j][highB | 0], acc);
            acc = cfma(cmul(hu0, lv1), A[0][j][highB | 1], acc);
            acc = cfma(cmul(hu1, lv0), A[0][j][highB | 2], acc);
            acc = cfma(cmul(hu1, lv1), A[0][j][highB | 3], acc);
            A[1][j][sidx] = acc;
        }
        __syncthreads();
    }

    // ================= Layer 1 (layer-0 ring perm folded into reads) =====
    {
        const Gate g0 = mkgate(wv[12], wv[13], wv[14]);
        const Gate g1 = mkgate(wv[15], wv[16], wv[17]);
        const Gate g2 = mkgate(wv[18], wv[19], wv[20]);
        const Gate g3 = mkgate(wv[21], wv[22], wv[23]);

        // L1A: wires 0,1; source index i -> sigma0(i), sigma0 = ringperm(.,1)
        {
            constexpr int p1 = ringperm(1, 1), p2 = ringperm(2, 1);
            constexpr int p4 = ringperm(4, 1), p8 = ringperm(8, 1);
            const int sl  = (b1 ? p2 : 0) ^ (b0 ? p1 : 0);  // sigma0(lowA)
            const float2 hu0 = csel(b3, g0.e10, g0.e00), hu1 = csel(b3, g0.e11, g0.e01);
            const float2 lv0 = csel(b2, g1.e10, g1.e00), lv1 = csel(b2, g1.e11, g1.e01);
            float2 acc = make_float2(0.f, 0.f);
            acc = cfma(cmul(hu0, lv0), A[1][j][sl],           acc);
            acc = cfma(cmul(hu0, lv1), A[1][j][sl ^ p4],      acc);
            acc = cfma(cmul(hu1, lv0), A[1][j][sl ^ p8],      acc);
            acc = cfma(cmul(hu1, lv1), A[1][j][sl ^ p4 ^ p8], acc);
            A[0][j][sidx] = acc;
        }
        __syncthreads();

        // L1B: wires 2,3; read A[0] -> write A[1]
        {
            const float2 hu0 = csel(b1, g2.e10, g2.e00), hu1 = csel(b1, g2.e11, g2.e01);
            const float2 lv0 = csel(b0, g3.e10, g3.e00), lv1 = csel(b0, g3.e11, g3.e01);
            float2 acc = make_float2(0.f, 0.f);
            acc = cfma(cmul(hu0, lv0), A[0][j][highB | 0], acc);
            acc = cfma(cmul(hu0, lv1), A[0][j][highB | 1], acc);
            acc = cfma(cmul(hu1, lv0), A[0][j][highB | 2], acc);
            acc = cfma(cmul(hu1, lv1), A[0][j][highB | 3], acc);
            A[1][j][sidx] = acc;
        }
        __syncthreads();
    }

    // ---- trig for the contraction (fills LDS-latency bubbles here) ----
    float c[4][NE], s[4][NE];
    #pragma unroll
    for (int jj = 0; jj < NE; ++jj) {
        s[0][jj] = __sinf(xv[jj].x); c[0][jj] = __cosf(xv[jj].x);
        s[1][jj] = __sinf(xv[jj].y); c[1][jj] = __cosf(xv[jj].y);
        s[2][jj] = __sinf(xv[jj].z); c[2][jj] = __cosf(xv[jj].z);
        s[3][jj] = __sinf(xv[jj].w); c[3][jj] = __cosf(xv[jj].w);
    }

    // ---- Stage B: M_k[row][col] = sum_tp conj(U[tp,row]) o_k[tp] U[tp,col]
    // Final ring perm (sigma1 = ringperm(.,2)) folded: U[tp][c] = A[1][c][sigma1(tp)]
    {
        const int row = j, col = sidx;
        float2 m0 = make_float2(0.f, 0.f), m1 = make_float2(0.f, 0.f);
        #pragma unroll
        for (int tp = 0; tp < 16; ++tp) {
            const int sp = ringperm(tp, 2);
            const float z0 = 1.f - 2.f * ((tp >> 3) & 1);
            const float z1 = 1.f - 2.f * ((tp >> 2) & 1);
            const float o0 = FW.x * z0 + FW.y * z1;
            const float o1 = FW.z * z0 + FW.w * z1;
            const float2 u = A[1][row][sp];
            const float2 v = A[1][col][sp];
            const float2 cc = make_float2(u.x * v.x + u.y * v.y,
                                          u.x * v.y - u.y * v.x);
            m0.x += o0 * cc.x; m0.y += o0 * cc.y;
            m1.x += o1 * cc.x; m1.y += o1 * cc.y;
        }
        M[0][row][col] = m0;
        M[1][row][col] = m1;
    }
    __syncthreads();

    // ---- Stage C: T_k[a] = Re sum_ss M_k[ss][ss^mY] * f(a,ss)
    if (t < 162) {
        const int k = t / 81, idx = t % 81;
        const int aa[4] = {idx / 27, (idx / 9) % 3, (idx / 3) % 3, idx % 3};
        int mZ = 0, mY = 0, nY = 0;
        #pragma unroll
        for (int q = 0; q < 4; ++q) {
            if (aa[q] == 1) mZ |= 1 << (3 - q);
            else if (aa[q] == 2) { mY |= 1 << (3 - q); ++nY; }
        }
        const int  mZY   = mZ | mY;
        const bool pickY = nY & 1;
        const int  baseS = ((nY & 3) == 1 || (nY & 3) == 2) ? 1 : 0;
        const int  k0    = (nY + baseS) & 1;
        float acc = 0.f;
        #pragma unroll
        for (int ss = 0; ss < 16; ++ss) {
            const float2 m = M[k][ss][ss ^ mY];
            const float  v = pickY ? m.y : m.x;
            acc += ((__popc(ss & mZY) + k0) & 1) ? -v : v;
        }
        acc *= 0.0625f;
        if (idx == 0) acc += (k == 0 ? FB.x : FB.y);
        Ts[t] = acc;
    }
    __syncthreads();

    // ================= main contraction =================
    float res0[NE], res1[NE];
    #pragma unroll
    for (int k = 0; k < 2; ++k) {
        float fa[NE];
        #pragma unroll
        for (int a0 = 0; a0 < 3; ++a0) {
            float ga[NE];
            #pragma unroll
            for (int a1 = 0; a1 < 3; ++a1) {
                float ea[NE];
                #pragma unroll
                for (int a2 = 0; a2 < 3; ++a2) {
                    const int base = (((k * 3 + a0) * 3 + a1) * 3 + a2) * 3;
                    const float t0 = Ts[base + 0];
                    const float t1 = Ts[base + 1];
                    const float t2 = Ts[base + 2];
                    #pragma unroll
                    for (int jj = 0; jj < NE; ++jj) {
                        const float d = __builtin_fmaf(s[3][jj], t2,
                                        __builtin_fmaf(c[3][jj], t1, t0));
                        if (a2 == 0)      ea[jj] = d;
                        else if (a2 == 1) ea[jj] = __builtin_fmaf(c[2][jj], d, ea[jj]);
                        else              ea[jj] = __builtin_fmaf(s[2][jj], d, ea[jj]);
                    }
                }
                #pragma unroll
                for (int jj = 0; jj < NE; ++jj) {
                    if (a1 == 0)      ga[jj] = ea[jj];
                    else if (a1 == 1) ga[jj] = __builtin_fmaf(c[1][jj], ea[jj], ga[jj]);
                    else              ga[jj] = __builtin_fmaf(s[1][jj], ea[jj], ga[jj]);
                }
            }
            #pragma unroll
            for (int jj = 0; jj < NE; ++jj) {
                if (a0 == 0)      fa[jj] = ga[jj];
                else if (a0 == 1) fa[jj] = __builtin_fmaf(c[0][jj], ga[jj], fa[jj]);
                else              fa[jj] = __builtin_fmaf(s[0][jj], ga[jj], fa[jj]);
            }
        }
        #pragma unroll
        for (int jj = 0; jj < NE; ++jj) {
            if (k == 0) res0[jj] = fa[jj]; else res1[jj] = fa[jj];
        }
    }

    #pragma unroll
    for (int jj = 0; jj < NE; ++jj)
        if (ei[jj] < B) out[ei[jj]] = make_float2(res0[jj], res1[jj]);
}

extern "C" void kernel_launch(void* const* d_in, const int* in_sizes, int n_in,
                              void* d_out, int out_size, void* d_ws, size_t ws_size,
                              hipStream_t stream) {
    const float* x   = (const float*)d_in[0];   // [B,4]
    const float* w   = (const float*)d_in[1];   // [2,4,3]
    const float* fcw = (const float*)d_in[2];   // [2,2]
    const float* fcb = (const float*)d_in[3];   // [2]
    const int B = in_sizes[0] / 4;

    constexpr int NE = 4;
    const int threads = (B + NE - 1) / NE;
    const int blocks  = (threads + 255) / 256;
    qnet_fused<NE><<<blocks, 256, 0, stream>>>(
        (const float4*)x, w, fcw, fcb, (float2*)d_out, B);
}